// Round 1
// baseline (433.560 us; speedup 1.0000x reference)
//
#include <hip/hip_runtime.h>

typedef __attribute__((ext_vector_type(2))) float fvec2;
typedef __attribute__((ext_vector_type(4))) float fvec4;

// low:   [N=4][C=64][H=256][W=256] f32
// highs: [N][C][3][H][W] f32  (planes: lh, hl, hh)
// out:   [N][C][512][512] f32
// Inverse Haar-style DWT (L=2 synthesis): every output 2x2 quad is a
// 4-input butterfly:
//   y[2m+dr][2n+dc] = (low*g0c[dr] + lh*g1c[dr])*g0r[dc]
//                   + (hl*g0c[dr] + hh*g1c[dr])*g1r[dc]
//
// Mapping chosen so EVERY memory instruction is contiguous across the wave:
//   lane i loads float2 at input col 2i      (512 B/wave/instr, coalesced)
//   lane i stores fvec4 at output col 4i     (1 KiB/wave/instr, coalesced,
//                                             full 128B lines -> no RFO)
// Each thread handles two column groups (cols 2i and 2i+128) of one (nc, m).
__global__ __launch_bounds__(256) void idwt2_kernel(
    const float* __restrict__ low,
    const float* __restrict__ highs,
    const float* __restrict__ g0c, const float* __restrict__ g1c,
    const float* __restrict__ g0r, const float* __restrict__ g1r,
    float* __restrict__ out)
{
    const int tid  = blockIdx.x * 256 + threadIdx.x;
    const int lane = tid & 63;         // column-pair group within the row
    const int m    = (tid >> 6) & 255; // input row
    const int nc   = tid >> 14;        // n*C + c, 0..255

    // synthesis filter taps (wave-uniform -> scalar loads)
    const float a0 = g0c[0], a1 = g0c[1];   // g0_col
    const float b0 = g1c[0], b1 = g1c[1];   // g1_col
    const float p0 = g0r[0], p1 = g0r[1];   // g0_row
    const float q0 = g1r[0], q1 = g1r[1];   // g1_row

    const size_t plane   = 65536;  // 256*256
    const size_t in_base = (size_t)nc * plane + (size_t)m * 256;
    const size_t h_base  = (size_t)nc * 3 * plane + (size_t)m * 256;

    const int c0 = 2 * lane;         // group 0: input cols [0,128)
    const int c1 = 2 * lane + 128;   // group 1: input cols [128,256)

    // Issue all 8 loads up front (max memory-level parallelism).
    const fvec2 l0  = *(const fvec2*)(low   + in_base + c0);
    const fvec2 l1  = *(const fvec2*)(low   + in_base + c1);
    const fvec2 lh0 = *(const fvec2*)(highs + h_base + c0);
    const fvec2 lh1 = *(const fvec2*)(highs + h_base + c1);
    const fvec2 hl0 = *(const fvec2*)(highs + h_base + plane + c0);
    const fvec2 hl1 = *(const fvec2*)(highs + h_base + plane + c1);
    const fvec2 hh0 = *(const fvec2*)(highs + h_base + 2 * plane + c0);
    const fvec2 hh1 = *(const fvec2*)(highs + h_base + 2 * plane + c1);

    // output rows 2m, 2m+1; group 0 -> cols [4i,4i+4), group 1 -> +256
    const size_t orow = ((size_t)nc * 512 + (size_t)(2 * m)) * 512;

    #pragma unroll
    for (int dr = 0; dr < 2; ++dr) {
        const float a = dr ? a1 : a0;   // g0_col[dr]
        const float b = dr ? b1 : b0;   // g1_col[dr]
        fvec4 o0, o1;
        #pragma unroll
        for (int j = 0; j < 2; ++j) {
            {
                const float lov = l0[j]  * a + lh0[j] * b;  // col-pass lo
                const float hiv = hl0[j] * a + hh0[j] * b;  // col-pass hi
                o0[2 * j]     = lov * p0 + hiv * q0;        // out col even
                o0[2 * j + 1] = lov * p1 + hiv * q1;        // out col odd
            }
            {
                const float lov = l1[j]  * a + lh1[j] * b;
                const float hiv = hl1[j] * a + hh1[j] * b;
                o1[2 * j]     = lov * p0 + hiv * q0;
                o1[2 * j + 1] = lov * p1 + hiv * q1;
            }
        }
        *(fvec4*)(out + orow + (size_t)dr * 512 + 4 * lane)       = o0;
        *(fvec4*)(out + orow + (size_t)dr * 512 + 256 + 4 * lane) = o1;
    }
}

extern "C" void kernel_launch(void* const* d_in, const int* in_sizes, int n_in,
                              void* d_out, int out_size, void* d_ws, size_t ws_size,
                              hipStream_t stream) {
    const float* low   = (const float*)d_in[0];
    const float* highs = (const float*)d_in[1];
    const float* g0c   = (const float*)d_in[2];
    const float* g1c   = (const float*)d_in[3];
    const float* g0r   = (const float*)d_in[4];
    const float* g1r   = (const float*)d_in[5];
    float* out = (float*)d_out;

    // total threads = N*C*H*(W/4) = 4*64*256*64 = 4,194,304 -> 16384 blocks
    idwt2_kernel<<<dim3(16384), dim3(256), 0, stream>>>(low, highs, g0c, g1c,
                                                        g0r, g1r, out);
}

// Round 2
// 425.450 us; speedup vs baseline: 1.0191x; 1.0191x over previous
//
#include <hip/hip_runtime.h>

typedef __attribute__((ext_vector_type(2))) float fvec2;
typedef __attribute__((ext_vector_type(4))) float fvec4;

// low:   [N=4][C=64][H=256][W=256] f32
// highs: [N][C][3][H][W] f32  (planes: lh, hl, hh)
// out:   [N][C][512][512] f32
// Inverse DWT (L=2 synthesis): every output 2x2 quad is a 4-input butterfly:
//   y[2m+dr][2n+dc] = (low*g0c[dr] + lh*g1c[dr])*g0r[dc]
//                   + (hl*g0c[dr] + hh*g1c[dr])*g1r[dc]
//
// Mapping: every memory instruction is contiguous across the wave:
//   lane i loads float2 at input col 2i   (512 B/wave/instr, full lines)
//   lane i stores fvec4 at output col 4i  (1 KiB/wave/instr, full lines)
// Streaming op, zero reuse, working set 537 MB > L3 -> non-temporal
// loads/stores bypass cache allocation (no pollution, no writeback cost).
// Grid-stride over nc (8 iters/thread) at 2048 blocks = 32 waves/CU.
__global__ __launch_bounds__(256) void idwt2_kernel(
    const float* __restrict__ low,
    const float* __restrict__ highs,
    const float* __restrict__ g0c, const float* __restrict__ g1c,
    const float* __restrict__ g0r, const float* __restrict__ g1r,
    float* __restrict__ out)
{
    const int tid  = blockIdx.x * 256 + threadIdx.x;  // 0..524287
    const int lane = tid & 63;         // column-pair group within the row
    const int m    = (tid >> 6) & 255; // input row
    const int nc0  = tid >> 14;        // 0..31; nc = nc0 + 32*k

    // synthesis filter taps (wave-uniform -> scalar loads)
    const float a0 = g0c[0], a1 = g0c[1];   // g0_col
    const float b0 = g1c[0], b1 = g1c[1];   // g1_col
    const float p0 = g0r[0], p1 = g0r[1];   // g0_row
    const float q0 = g1r[0], q1 = g1r[1];   // g1_row

    const size_t plane = 65536;  // 256*256
    const int c0 = 2 * lane;         // group 0: input cols [0,128)
    const int c1 = 2 * lane + 128;   // group 1: input cols [128,256)

    // 8 nc-chunks per thread; unroll 2 for cross-iteration load pipelining
    // without blowing VGPRs (full unroll-8 would hold 64 loads live).
    #pragma unroll 2
    for (int k = 0; k < 8; ++k) {
        const int nc = nc0 + 32 * k;
        const size_t in_base = (size_t)nc * plane + (size_t)m * 256;
        const size_t h_base  = (size_t)nc * 3 * plane + (size_t)m * 256;

        // Issue all 8 loads up front (max memory-level parallelism).
        const fvec2 l0  = __builtin_nontemporal_load((const fvec2*)(low   + in_base + c0));
        const fvec2 l1  = __builtin_nontemporal_load((const fvec2*)(low   + in_base + c1));
        const fvec2 lh0 = __builtin_nontemporal_load((const fvec2*)(highs + h_base + c0));
        const fvec2 lh1 = __builtin_nontemporal_load((const fvec2*)(highs + h_base + c1));
        const fvec2 hl0 = __builtin_nontemporal_load((const fvec2*)(highs + h_base + plane + c0));
        const fvec2 hl1 = __builtin_nontemporal_load((const fvec2*)(highs + h_base + plane + c1));
        const fvec2 hh0 = __builtin_nontemporal_load((const fvec2*)(highs + h_base + 2 * plane + c0));
        const fvec2 hh1 = __builtin_nontemporal_load((const fvec2*)(highs + h_base + 2 * plane + c1));

        // output rows 2m, 2m+1; group 0 -> cols [4*lane,+4), group 1 -> +256
        const size_t orow = ((size_t)nc * 512 + (size_t)(2 * m)) * 512;

        #pragma unroll
        for (int dr = 0; dr < 2; ++dr) {
            const float a = dr ? a1 : a0;   // g0_col[dr]
            const float b = dr ? b1 : b0;   // g1_col[dr]
            fvec4 o0, o1;
            #pragma unroll
            for (int j = 0; j < 2; ++j) {
                {
                    const float lov = l0[j]  * a + lh0[j] * b;  // col-pass lo
                    const float hiv = hl0[j] * a + hh0[j] * b;  // col-pass hi
                    o0[2 * j]     = lov * p0 + hiv * q0;        // out col even
                    o0[2 * j + 1] = lov * p1 + hiv * q1;        // out col odd
                }
                {
                    const float lov = l1[j]  * a + lh1[j] * b;
                    const float hiv = hl1[j] * a + hh1[j] * b;
                    o1[2 * j]     = lov * p0 + hiv * q0;
                    o1[2 * j + 1] = lov * p1 + hiv * q1;
                }
            }
            __builtin_nontemporal_store(o0, (fvec4*)(out + orow + (size_t)dr * 512 + 4 * lane));
            __builtin_nontemporal_store(o1, (fvec4*)(out + orow + (size_t)dr * 512 + 256 + 4 * lane));
        }
    }
}

extern "C" void kernel_launch(void* const* d_in, const int* in_sizes, int n_in,
                              void* d_out, int out_size, void* d_ws, size_t ws_size,
                              hipStream_t stream) {
    const float* low   = (const float*)d_in[0];
    const float* highs = (const float*)d_in[1];
    const float* g0c   = (const float*)d_in[2];
    const float* g1c   = (const float*)d_in[3];
    const float* g0r   = (const float*)d_in[4];
    const float* g1r   = (const float*)d_in[5];
    float* out = (float*)d_out;

    // 2048 blocks x 256 threads x 8 nc-iters = 4,194,304 work items
    idwt2_kernel<<<dim3(2048), dim3(256), 0, stream>>>(low, highs, g0c, g1c,
                                                       g0r, g1r, out);
}